// Round 1
// baseline (1267.756 us; speedup 1.0000x reference)
//
#include <hip/hip_runtime.h>

// LightGCN forward:
//   deg[i]   = #edges with row==i, +1 self loop
//   inv_deg  = 1/(deg+1e-8);  deg2 = deg*inv_deg;  inv_sqrt = rsqrt(deg2+1e-8)
//   a[i] = inv_sqrt[i]*inv_deg[i]   (row factor)
//   b[i] = inv_sqrt[i]              (col factor)
//   h[r] = sum_e a[r]*b[c]*x[c]  (+ self term a[i]*b[i]*x[i])

#define D 64  // embed dim

__global__ void deg_count_kernel(const int* __restrict__ rows,
                                 int* __restrict__ cnt, int E) {
    int e = blockIdx.x * blockDim.x + threadIdx.x;
    int stride = gridDim.x * blockDim.x;
    for (; e < E; e += stride) {
        atomicAdd(&cnt[rows[e]], 1);
    }
}

__global__ void node_init_kernel(const float* __restrict__ x,
                                 const int* __restrict__ cnt,
                                 float* __restrict__ a, float* __restrict__ b,
                                 float* __restrict__ h, int n) {
    int t = blockIdx.x * blockDim.x + threadIdx.x;
    int i = t >> 6;
    int j = t & 63;
    if (i >= n) return;
    float degf = (float)(cnt[i] + 1);          // +1 self loop
    float inv_deg = 1.0f / (degf + 1e-8f);
    float deg2 = degf * inv_deg;
    float inv_sqrt = rsqrtf(deg2 + 1e-8f);
    float ai = inv_sqrt * inv_deg;
    float bi = inv_sqrt;
    if (j == 0) { a[i] = ai; b[i] = bi; }
    // self-loop contribution initializes h
    h[t] = ai * bi * x[t];
}

__global__ void edge_scatter_kernel(const int* __restrict__ rows,
                                    const int* __restrict__ cols,
                                    const float* __restrict__ a,
                                    const float* __restrict__ b,
                                    const float* __restrict__ x,
                                    float* __restrict__ h, int E) {
    int gid = blockIdx.x * blockDim.x + threadIdx.x;
    int wave = gid >> 6;          // one 64-lane wave per edge
    int j = gid & 63;
    int nwaves = (gridDim.x * blockDim.x) >> 6;
    for (int e = wave; e < E; e += nwaves) {
        int r = rows[e];
        int c = cols[e];
        float w = a[r] * b[c];                 // wave-uniform (broadcast loads)
        float v = w * x[c * D + j];            // coalesced 256B gather per edge
        atomicAdd(&h[r * D + j], v);           // coalesced f32 atomics
    }
}

extern "C" void kernel_launch(void* const* d_in, const int* in_sizes, int n_in,
                              void* d_out, int out_size, void* d_ws, size_t ws_size,
                              hipStream_t stream) {
    const float* x = (const float*)d_in[0];
    const int* edge = (const int*)d_in[1];     // [2, E] flattened row-major
    float* h = (float*)d_out;

    int n = in_sizes[0] / D;                   // 200000
    int E = in_sizes[1] / 2;                   // 5000000
    const int* rows = edge;
    const int* cols = edge + E;

    // workspace layout: cnt[n] int | a[n] float | b[n] float
    int* cnt = (int*)d_ws;
    float* a = (float*)((char*)d_ws + (size_t)n * sizeof(int));
    float* b = (float*)((char*)d_ws + (size_t)n * sizeof(int) + (size_t)n * sizeof(float));

    hipMemsetAsync(cnt, 0, (size_t)n * sizeof(int), stream);

    {   // degree histogram
        int block = 256;
        int grid = 2048;
        deg_count_kernel<<<grid, block, 0, stream>>>(rows, cnt, E);
    }
    {   // per-node factors + self-loop init of h
        int block = 256;
        int grid = (n * D + block - 1) / block;
        node_init_kernel<<<grid, block, 0, stream>>>(x, cnt, a, b, h, n);
    }
    {   // edge scatter-add
        int block = 256;
        int grid = 8192;  // 32K waves resident, grid-stride over edges
        edge_scatter_kernel<<<grid, block, 0, stream>>>(rows, cols, a, b, x, h, E);
    }
}

// Round 2
// 827.772 us; speedup vs baseline: 1.5315x; 1.5315x over previous
//
#include <hip/hip_runtime.h>

// LightGCN forward via device-built CSR + gather SpMM (no output atomics).
//   deg[i]  = #edges with row==i (+1 self loop in factors)
//   a[i] = inv_sqrt*inv_deg, b[i] = inv_sqrt
//   h[r] = a[r] * ( b[r]*x[r] + sum_{e in row r} b[c_e]*x[c_e] )

#define D 64
#define SCAN_BLK 1024

__global__ void deg_count_kernel(const int* __restrict__ rows,
                                 int* __restrict__ cnt, int E) {
    int e = blockIdx.x * blockDim.x + threadIdx.x;
    int stride = gridDim.x * blockDim.x;
    for (; e < E; e += stride) atomicAdd(&cnt[rows[e]], 1);
}

__global__ void factors_kernel(const int* __restrict__ cnt,
                               float* __restrict__ a, float* __restrict__ b, int n) {
    int i = blockIdx.x * blockDim.x + threadIdx.x;
    if (i >= n) return;
    float degf = (float)(cnt[i] + 1);          // +1 self loop
    float inv_deg = 1.0f / (degf + 1e-8f);
    float deg2 = degf * inv_deg;
    float inv_sqrt = rsqrtf(deg2 + 1e-8f);
    a[i] = inv_sqrt * inv_deg;
    b[i] = inv_sqrt;
}

// scan step 1: per-block exclusive scan of cnt -> row_start (local), block sums -> bsum
__global__ void scan1_kernel(const int* __restrict__ cnt, int* __restrict__ row_start,
                             int* __restrict__ bsum, int n) {
    __shared__ int sm[SCAN_BLK];
    int tid = threadIdx.x;
    int i = blockIdx.x * SCAN_BLK + tid;
    int v = (i < n) ? cnt[i] : 0;
    sm[tid] = v;
    __syncthreads();
    for (int off = 1; off < SCAN_BLK; off <<= 1) {
        int t = (tid >= off) ? sm[tid - off] : 0;
        __syncthreads();
        sm[tid] += t;
        __syncthreads();
    }
    if (i < n) row_start[i] = sm[tid] - v;      // exclusive
    if (tid == SCAN_BLK - 1) bsum[blockIdx.x] = sm[tid];
}

// scan step 2: serial exclusive scan of block sums (NB ~ 196, trivial)
__global__ void scan2_kernel(int* __restrict__ bsum, int nb) {
    if (blockIdx.x == 0 && threadIdx.x == 0) {
        int run = 0;
        for (int i = 0; i < nb; ++i) { int v = bsum[i]; bsum[i] = run; run += v; }
    }
}

// scan step 3: add block offsets; write sentinel row_start[n] = E
__global__ void scan3_kernel(int* __restrict__ row_start, const int* __restrict__ bsum,
                             int n, int E) {
    int i = blockIdx.x * SCAN_BLK + threadIdx.x;
    if (i < n) row_start[i] += bsum[blockIdx.x];
    if (i == 0) row_start[n] = E;
}

// scatter edges into CSR order; consumes cnt as a countdown
__global__ void csr_fill_kernel(const int* __restrict__ rows, const int* __restrict__ cols,
                                const int* __restrict__ row_start, int* __restrict__ cnt,
                                int* __restrict__ col_sorted, int E) {
    int e = blockIdx.x * blockDim.x + threadIdx.x;
    int stride = gridDim.x * blockDim.x;
    for (; e < E; e += stride) {
        int r = rows[e];
        int old = atomicSub(&cnt[r], 1);
        col_sorted[row_start[r] + old - 1] = cols[e];
    }
}

// gather SpMM: one wave per row, lane j owns dim j
__global__ void spmm_kernel(const int* __restrict__ row_start,
                            const int* __restrict__ col_sorted,
                            const float* __restrict__ a, const float* __restrict__ b,
                            const float* __restrict__ x, float* __restrict__ h, int n) {
    int gid = blockIdx.x * blockDim.x + threadIdx.x;
    int r = gid >> 6;
    int j = gid & 63;
    if (r >= n) return;
    int s = row_start[r];
    int e = row_start[r + 1];
    float acc0 = b[r] * x[(size_t)r * D + j];   // self loop
    float acc1 = 0.f;
    int k = s;
    for (; k + 1 < e; k += 2) {
        int c0 = col_sorted[k];
        int c1 = col_sorted[k + 1];
        acc0 += b[c0] * x[(size_t)c0 * D + j];
        acc1 += b[c1] * x[(size_t)c1 * D + j];
    }
    if (k < e) {
        int c = col_sorted[k];
        acc0 += b[c] * x[(size_t)c * D + j];
    }
    h[(size_t)r * D + j] = a[r] * (acc0 + acc1);
}

extern "C" void kernel_launch(void* const* d_in, const int* in_sizes, int n_in,
                              void* d_out, int out_size, void* d_ws, size_t ws_size,
                              hipStream_t stream) {
    const float* x = (const float*)d_in[0];
    const int* edge = (const int*)d_in[1];
    float* h = (float*)d_out;

    int n = in_sizes[0] / D;                   // 200000
    int E = in_sizes[1] / 2;                   // 5000000
    const int* rows = edge;
    const int* cols = edge + E;
    int NB = (n + SCAN_BLK - 1) / SCAN_BLK;    // 196

    // ws layout: cnt[n] | row_start[n+1] | bsum[NB] | a[n] | b[n] | col_sorted[E]
    char* p = (char*)d_ws;
    int* cnt       = (int*)p;                  p += (size_t)n * 4;
    int* row_start = (int*)p;                  p += (size_t)(n + 1) * 4;
    int* bsum      = (int*)p;                  p += (size_t)NB * 4;
    float* a       = (float*)p;                p += (size_t)n * 4;
    float* b       = (float*)p;                p += (size_t)n * 4;
    int* col_sorted= (int*)p;

    hipMemsetAsync(cnt, 0, (size_t)n * sizeof(int), stream);

    deg_count_kernel<<<2048, 256, 0, stream>>>(rows, cnt, E);
    factors_kernel<<<(n + 255) / 256, 256, 0, stream>>>(cnt, a, b, n);
    scan1_kernel<<<NB, SCAN_BLK, 0, stream>>>(cnt, row_start, bsum, n);
    scan2_kernel<<<1, 64, 0, stream>>>(bsum, NB);
    scan3_kernel<<<NB, SCAN_BLK, 0, stream>>>(row_start, bsum, n, E);
    csr_fill_kernel<<<2048, 256, 0, stream>>>(rows, cols, row_start, cnt, col_sorted, E);
    spmm_kernel<<<(n * D + 255) / 256, 256, 0, stream>>>(row_start, col_sorted, a, b, x, h, n);
}